// Round 2
// baseline (515.627 us; speedup 1.0000x reference)
//
#include <hip/hip_runtime.h>

#define GLN_SIZE 1024
#define GLN_INPUT 1024
#define GLN_CTX 512
#define GLN_CMS 6
#define GLN_NCTX 64        // 2^CMS
#define GLN_BATCH 128
#define GLN_LR 0.01f
#define GLN_OUT_CLIP 0.01f
#define GLN_W_CLIP 5.0f

typedef float f32x4 __attribute__((ext_vector_type(4)));

// ---------------------------------------------------------------------------
// Kernel 1: transpose logits (INPUT, BATCH) -> logitsT (BATCH, INPUT)
// ---------------------------------------------------------------------------
__global__ __launch_bounds__(256) void transpose_kernel(
    const float* __restrict__ in,   // (1024, 128)
    float* __restrict__ out)        // (128, 1024)
{
    __shared__ float tile[32][33];
    const int bx = blockIdx.x * 32;   // BATCH dim
    const int by = blockIdx.y * 32;   // INPUT dim
    const int tx = threadIdx.x;       // 0..31
    const int ty = threadIdx.y;       // 0..7
#pragma unroll
    for (int j = 0; j < 32; j += 8) {
        int r = by + ty + j;          // input row
        int c = bx + tx;              // batch col
        tile[ty + j][tx] = in[r * GLN_BATCH + c];
    }
    __syncthreads();
#pragma unroll
    for (int j = 0; j < 32; j += 8) {
        int b = bx + ty + j;          // batch row in output
        int r = by + tx;              // input col in output
        out[b * GLN_INPUT + r] = tile[tx][ty + j];
    }
}

// ---------------------------------------------------------------------------
// Kernel 2: context hashing. One block (128 threads) per neuron s.
// idx[s][b] = sum_m ( (proj[s][m] . ctx[:,b]) > pbias[s][m] ) << m
// ---------------------------------------------------------------------------
__global__ __launch_bounds__(128) void hash_kernel(
    const float* __restrict__ ctx,    // (512, 128)
    const float* __restrict__ proj,   // (1024, 6, 512)
    const float* __restrict__ pbias,  // (1024, 6, 1)
    int* __restrict__ idx)            // (1024, 128)
{
    const int s = blockIdx.x;
    const int b = threadIdx.x;        // 0..127

    __shared__ float pl[GLN_CMS][GLN_CTX];   // 12 KiB
    const f32x4* p4 = (const f32x4*)(proj + (size_t)s * GLN_CMS * GLN_CTX);
    f32x4* pl4 = (f32x4*)&pl[0][0];
#pragma unroll
    for (int t = b; t < GLN_CMS * GLN_CTX / 4; t += 128) pl4[t] = p4[t];
    __syncthreads();

    float acc[GLN_CMS] = {0.f, 0.f, 0.f, 0.f, 0.f, 0.f};
    for (int c = 0; c < GLN_CTX; ++c) {
        float v = ctx[c * GLN_BATCH + b];   // coalesced across threads
#pragma unroll
        for (int m = 0; m < GLN_CMS; ++m) acc[m] += pl[m][c] * v;
    }
    int v = 0;
#pragma unroll
    for (int m = 0; m < GLN_CMS; ++m)
        v |= (acc[m] > pbias[s * GLN_CMS + m]) ? (1 << m) : 0;
    idx[s * GLN_BATCH + b] = v;
}

// ---------------------------------------------------------------------------
// Kernel 3: fused out + update + weights copy. One block (256 thr = 4 waves)
// per neuron s. Each wave owns 16 context rows; each row is loaded once into
// registers (nontemporal — stream-once data), dots for its bucket computed,
// winner update applied, row stored nontemporally.
// ---------------------------------------------------------------------------
__global__ __launch_bounds__(256) void gln_kernel(
    const float* __restrict__ weights,  // (1024, 64, 1024)
    const float* __restrict__ logitsT,  // (128, 1024)
    const float* __restrict__ targets,  // (128)
    const float* __restrict__ biasPtr,  // (1)
    const int* __restrict__ idx,        // (1024, 128)
    float* __restrict__ outv,           // (1024, 128)   [d_out part 1]
    float* __restrict__ outw)           // (1024,64,1024)[d_out part 2]
{
    const int s    = blockIdx.x;
    const int tid  = threadIdx.x;
    const int lane = tid & 63;
    const int wv   = tid >> 6;          // wave id 0..3

    __shared__ int cnt[GLN_NCTX];
    __shared__ int winner[GLN_NCTX];
    __shared__ unsigned char lists[GLN_NCTX][GLN_BATCH];   // 8 KiB

    if (tid < GLN_NCTX) { cnt[tid] = 0; winner[tid] = -1; }
    __syncthreads();
    if (tid < GLN_BATCH) {
        int c = idx[s * GLN_BATCH + tid];
        int slot = atomicAdd(&cnt[c], 1);
        lists[c][slot] = (unsigned char)tid;
        atomicMax(&winner[c], tid);
    }
    __syncthreads();

    const float bias = biasPtr[0];
    const float* wrow_base = weights + (size_t)s * GLN_NCTX * GLN_INPUT;
    float*       orow_base = outw    + (size_t)s * GLN_NCTX * GLN_INPUT;

    for (int c = wv * 16; c < wv * 16 + 16; ++c) {
        // Load weight row into registers: lane owns elems {lane*4+k*256 ..}
        f32x4 w4[4];
        const f32x4* wr = (const f32x4*)(wrow_base + c * GLN_INPUT);
#pragma unroll
        for (int k = 0; k < 4; ++k)
            w4[k] = __builtin_nontemporal_load(wr + lane + k * 64);

        const int n    = cnt[c];
        const int bwin = winner[c];
        float dwin = 0.0f;

        for (int u = 0; u < n; ++u) {
            const int b = lists[c][u];
            float outval;
            if (s != 0) {
                const f32x4* lg = (const f32x4*)(logitsT + b * GLN_INPUT);
                float p = 0.f;
#pragma unroll
                for (int k = 0; k < 4; ++k) {
                    f32x4 g = lg[lane + k * 64];
                    p += w4[k][0] * g[0] + w4[k][1] * g[1] +
                         w4[k][2] * g[2] + w4[k][3] * g[3];
                }
#pragma unroll
                for (int off = 1; off < 64; off <<= 1)
                    p += __shfl_xor(p, off, 64);
                outval = p;
            } else {
                outval = bias;   // reference overwrites row 0 with bias
            }
            float sg = 1.0f / (1.0f + expf(-outval));
            sg = fminf(fmaxf(sg, GLN_OUT_CLIP), 1.0f - GLN_OUT_CLIP);
            float d = GLN_LR * (sg - targets[b]);
            if (lane == 0) outv[s * GLN_BATCH + b] = outval;
            if (b == bwin) dwin = d;   // last-b-wins scatter semantics
        }

        // Write (possibly updated) row — nontemporal, stream-once
        f32x4* orow = (f32x4*)(orow_base + c * GLN_INPUT);
        if (bwin >= 0) {
            const f32x4* lg = (const f32x4*)(logitsT + bwin * GLN_INPUT);
#pragma unroll
            for (int k = 0; k < 4; ++k) {
                f32x4 g = lg[lane + k * 64];
                f32x4 r;
                r[0] = fminf(fmaxf(w4[k][0] - dwin * g[0], -GLN_W_CLIP), GLN_W_CLIP);
                r[1] = fminf(fmaxf(w4[k][1] - dwin * g[1], -GLN_W_CLIP), GLN_W_CLIP);
                r[2] = fminf(fmaxf(w4[k][2] - dwin * g[2], -GLN_W_CLIP), GLN_W_CLIP);
                r[3] = fminf(fmaxf(w4[k][3] - dwin * g[3], -GLN_W_CLIP), GLN_W_CLIP);
                __builtin_nontemporal_store(r, orow + lane + k * 64);
            }
        } else {
#pragma unroll
            for (int k = 0; k < 4; ++k)
                __builtin_nontemporal_store(w4[k], orow + lane + k * 64);
        }
    }
}

// ---------------------------------------------------------------------------
extern "C" void kernel_launch(void* const* d_in, const int* in_sizes, int n_in,
                              void* d_out, int out_size, void* d_ws, size_t ws_size,
                              hipStream_t stream) {
    const float* logits  = (const float*)d_in[0];  // (1024,128)
    const float* ctx     = (const float*)d_in[1];  // (512,128)
    const float* targets = (const float*)d_in[2];  // (128)
    const float* proj    = (const float*)d_in[3];  // (1024,6,512)
    const float* pbias   = (const float*)d_in[4];  // (1024,6,1)
    const float* weights = (const float*)d_in[5];  // (1024,64,1024)
    const float* bias    = (const float*)d_in[6];  // scalar

    float* outv = (float*)d_out;                       // (1024,128)
    float* outw = outv + GLN_SIZE * GLN_BATCH;         // (1024,64,1024)

    float* logitsT = (float*)d_ws;                     // 128*1024 floats
    int*   idx     = (int*)(logitsT + GLN_BATCH * GLN_INPUT);  // 1024*128 ints

    transpose_kernel<<<dim3(GLN_BATCH / 32, GLN_INPUT / 32), dim3(32, 8), 0, stream>>>(
        logits, logitsT);
    hash_kernel<<<GLN_SIZE, 128, 0, stream>>>(ctx, proj, pbias, idx);
    gln_kernel<<<GLN_SIZE, 256, 0, stream>>>(weights, logitsT, targets, bias,
                                             idx, outv, outw);
}

// Round 3
// 511.149 us; speedup vs baseline: 1.0088x; 1.0088x over previous
//
#include <hip/hip_runtime.h>

#define GLN_SIZE 1024
#define GLN_INPUT 1024
#define GLN_CTX 512
#define GLN_CMS 6
#define GLN_NCTX 64        // 2^CMS
#define GLN_BATCH 128
#define GLN_LR 0.01f
#define GLN_OUT_CLIP 0.01f
#define GLN_W_CLIP 5.0f

typedef float f32x4 __attribute__((ext_vector_type(4)));

// ---------------------------------------------------------------------------
// Kernel 1: transpose logits (INPUT, BATCH) -> logitsT (BATCH, INPUT)
// ---------------------------------------------------------------------------
__global__ __launch_bounds__(256) void transpose_kernel(
    const float* __restrict__ in,   // (1024, 128)
    float* __restrict__ out)        // (128, 1024)
{
    __shared__ float tile[32][33];
    const int bx = blockIdx.x * 32;   // BATCH dim
    const int by = blockIdx.y * 32;   // INPUT dim
    const int tx = threadIdx.x;       // 0..31
    const int ty = threadIdx.y;       // 0..7
#pragma unroll
    for (int j = 0; j < 32; j += 8) {
        int r = by + ty + j;          // input row
        int c = bx + tx;              // batch col
        tile[ty + j][tx] = in[r * GLN_BATCH + c];
    }
    __syncthreads();
#pragma unroll
    for (int j = 0; j < 32; j += 8) {
        int b = bx + ty + j;          // batch row in output
        int r = by + tx;              // input col in output
        out[b * GLN_INPUT + r] = tile[tx][ty + j];
    }
}

// ---------------------------------------------------------------------------
// Kernel 2: context hashing. One block (128 threads) per neuron s.
// idx[s][b] = sum_m ( (proj[s][m] . ctx[:,b]) > pbias[s][m] ) << m
// (unchanged from passing round — arithmetic order preserved so ctx_idx
//  bit-decisions stay identical)
// ---------------------------------------------------------------------------
__global__ __launch_bounds__(128) void hash_kernel(
    const float* __restrict__ ctx,    // (512, 128)
    const float* __restrict__ proj,   // (1024, 6, 512)
    const float* __restrict__ pbias,  // (1024, 6, 1)
    int* __restrict__ idx)            // (1024, 128)
{
    const int s = blockIdx.x;
    const int b = threadIdx.x;        // 0..127

    __shared__ float pl[GLN_CMS][GLN_CTX];   // 12 KiB
    const f32x4* p4 = (const f32x4*)(proj + (size_t)s * GLN_CMS * GLN_CTX);
    f32x4* pl4 = (f32x4*)&pl[0][0];
#pragma unroll
    for (int t = b; t < GLN_CMS * GLN_CTX / 4; t += 128) pl4[t] = p4[t];
    __syncthreads();

    float acc[GLN_CMS] = {0.f, 0.f, 0.f, 0.f, 0.f, 0.f};
    for (int c = 0; c < GLN_CTX; ++c) {
        float v = ctx[c * GLN_BATCH + b];   // coalesced across threads
#pragma unroll
        for (int m = 0; m < GLN_CMS; ++m) acc[m] += pl[m][c] * v;
    }
    int v = 0;
#pragma unroll
    for (int m = 0; m < GLN_CMS; ++m)
        v |= (acc[m] > pbias[s * GLN_CMS + m]) ? (1 << m) : 0;
    idx[s * GLN_BATCH + b] = v;
}

// ---------------------------------------------------------------------------
// Kernel 3: fused out + update + weights copy. One block (512 thr = 8 waves)
// per neuron s; each wave owns 8 context rows. Register double-buffer: row
// c+1's nontemporal load is issued before row c's dots, hiding HBM latency
// under the dot/update compute. Dot arithmetic order identical to the
// passing round.
// ---------------------------------------------------------------------------
__global__ __launch_bounds__(512, 4) void gln_kernel(
    const float* __restrict__ weights,  // (1024, 64, 1024)
    const float* __restrict__ logitsT,  // (128, 1024)
    const float* __restrict__ targets,  // (128)
    const float* __restrict__ biasPtr,  // (1)
    const int* __restrict__ idx,        // (1024, 128)
    float* __restrict__ outv,           // (1024, 128)   [d_out part 1]
    float* __restrict__ outw)           // (1024,64,1024)[d_out part 2]
{
    const int s    = blockIdx.x;
    const int tid  = threadIdx.x;
    const int lane = tid & 63;
    const int wv   = tid >> 6;          // wave id 0..7

    __shared__ int cnt[GLN_NCTX];
    __shared__ int winner[GLN_NCTX];
    __shared__ unsigned char lists[GLN_NCTX][GLN_BATCH];   // 8 KiB

    if (tid < GLN_NCTX) { cnt[tid] = 0; winner[tid] = -1; }
    __syncthreads();
    if (tid < GLN_BATCH) {
        int c = idx[s * GLN_BATCH + tid];
        int slot = atomicAdd(&cnt[c], 1);
        lists[c][slot] = (unsigned char)tid;
        atomicMax(&winner[c], tid);
    }
    __syncthreads();

    const float bias = biasPtr[0];
    const float* wrow_base = weights + (size_t)s * GLN_NCTX * GLN_INPUT;
    float*       orow_base = outw    + (size_t)s * GLN_NCTX * GLN_INPUT;

    // Preload first row of this wave's 8-row strip
    f32x4 w4[4], w4n[4];
    {
        const f32x4* wr = (const f32x4*)(wrow_base + (wv * 8) * GLN_INPUT);
#pragma unroll
        for (int k = 0; k < 4; ++k)
            w4[k] = __builtin_nontemporal_load(wr + lane + k * 64);
    }

#pragma unroll
    for (int ci = 0; ci < 8; ++ci) {
        const int c = wv * 8 + ci;

        // Prefetch next row (register double-buffer)
        if (ci < 7) {
            const f32x4* wrn = (const f32x4*)(wrow_base + (c + 1) * GLN_INPUT);
#pragma unroll
            for (int k = 0; k < 4; ++k)
                w4n[k] = __builtin_nontemporal_load(wrn + lane + k * 64);
        }

        const int n    = cnt[c];
        const int bwin = winner[c];
        float dwin = 0.0f;

        for (int u = 0; u < n; ++u) {
            const int b = lists[c][u];
            float outval;
            if (s != 0) {
                const f32x4* lg = (const f32x4*)(logitsT + b * GLN_INPUT);
                float p = 0.f;
#pragma unroll
                for (int k = 0; k < 4; ++k) {
                    f32x4 g = lg[lane + k * 64];
                    p += w4[k][0] * g[0] + w4[k][1] * g[1] +
                         w4[k][2] * g[2] + w4[k][3] * g[3];
                }
#pragma unroll
                for (int off = 1; off < 64; off <<= 1)
                    p += __shfl_xor(p, off, 64);
                outval = p;
            } else {
                outval = bias;   // reference overwrites row 0 with bias
            }
            float sg = 1.0f / (1.0f + expf(-outval));
            sg = fminf(fmaxf(sg, GLN_OUT_CLIP), 1.0f - GLN_OUT_CLIP);
            float d = GLN_LR * (sg - targets[b]);
            if (lane == 0) outv[s * GLN_BATCH + b] = outval;
            if (b == bwin) dwin = d;   // last-b-wins scatter semantics
        }

        // Write (possibly updated) row — nontemporal, stream-once
        f32x4* orow = (f32x4*)(orow_base + c * GLN_INPUT);
        if (bwin >= 0) {
            const f32x4* lg = (const f32x4*)(logitsT + bwin * GLN_INPUT);
#pragma unroll
            for (int k = 0; k < 4; ++k) {
                f32x4 g = lg[lane + k * 64];
                f32x4 r;
                r[0] = fminf(fmaxf(w4[k][0] - dwin * g[0], -GLN_W_CLIP), GLN_W_CLIP);
                r[1] = fminf(fmaxf(w4[k][1] - dwin * g[1], -GLN_W_CLIP), GLN_W_CLIP);
                r[2] = fminf(fmaxf(w4[k][2] - dwin * g[2], -GLN_W_CLIP), GLN_W_CLIP);
                r[3] = fminf(fmaxf(w4[k][3] - dwin * g[3], -GLN_W_CLIP), GLN_W_CLIP);
                __builtin_nontemporal_store(r, orow + lane + k * 64);
            }
        } else {
#pragma unroll
            for (int k = 0; k < 4; ++k)
                __builtin_nontemporal_store(w4[k], orow + lane + k * 64);
        }

        // Rotate double-buffer
#pragma unroll
        for (int k = 0; k < 4; ++k) w4[k] = w4n[k];
    }
}

// ---------------------------------------------------------------------------
extern "C" void kernel_launch(void* const* d_in, const int* in_sizes, int n_in,
                              void* d_out, int out_size, void* d_ws, size_t ws_size,
                              hipStream_t stream) {
    const float* logits  = (const float*)d_in[0];  // (1024,128)
    const float* ctx     = (const float*)d_in[1];  // (512,128)
    const float* targets = (const float*)d_in[2];  // (128)
    const float* proj    = (const float*)d_in[3];  // (1024,6,512)
    const float* pbias   = (const float*)d_in[4];  // (1024,6,1)
    const float* weights = (const float*)d_in[5];  // (1024,64,1024)
    const float* bias    = (const float*)d_in[6];  // scalar

    float* outv = (float*)d_out;                       // (1024,128)
    float* outw = outv + GLN_SIZE * GLN_BATCH;         // (1024,64,1024)

    float* logitsT = (float*)d_ws;                     // 128*1024 floats
    int*   idx     = (int*)(logitsT + GLN_BATCH * GLN_INPUT);  // 1024*128 ints

    transpose_kernel<<<dim3(GLN_BATCH / 32, GLN_INPUT / 32), dim3(32, 8), 0, stream>>>(
        logits, logitsT);
    hash_kernel<<<GLN_SIZE, 128, 0, stream>>>(ctx, proj, pbias, idx);
    gln_kernel<<<GLN_SIZE, 512, 0, stream>>>(weights, logitsT, targets, bias,
                                             idx, outv, outw);
}